// Round 10
// baseline (298.378 us; speedup 1.0000x reference)
//
#include <hip/hip_runtime.h>
#include <math.h>

// ConvSlimCapsule3D, round 14: r12 base (best, 212.5us) +
//  - r13's swapped-MFMA epilogue (proven: conflicts 4.78M -> 2.69M), with r12's
//    routing + scattered output stores (r13's OF bounce regressed HBM traffic).
//  - K-loop register-rotation prefetch: bf[nt] for chunk c+1 loaded right after
//    its last use in chunk c (zero extra live regs; ~14 MFMAs of latency cover).
//    Diagnosis: VGPR_Count=64 + 64 acc = exactly the 128 cap at (512,4) -> the
//    compiler could never software-pipeline; all r5-r13 variants identical 142us.
//  - chunk-0 bf loads issued BEFORE the staging barrier (latency hides in drain).
//  - prep_all unchanged from r12.

typedef _Float16 half8 __attribute__((ext_vector_type(8)));
typedef _Float16 half4 __attribute__((ext_vector_type(4)));
typedef float f32x4 __attribute__((ext_vector_type(4)));
typedef float f32x2 __attribute__((ext_vector_type(2)));

__device__ __forceinline__ void gload_lds16(const void* g, void* l) {
    __builtin_amdgcn_global_load_lds(
        (const __attribute__((address_space(1))) void*)g,
        (__attribute__((address_space(3))) void*)l, 16, 0, 0);
}

// lane^1 exchange on the VALU (DPP quad_perm(1,0,3,2)).
__device__ __forceinline__ float swap1(float x) {
    return __builtin_bit_cast(float, __builtin_amdgcn_update_dpp(
        0, __builtin_bit_cast(int, x), 0xB1, 0xF, 0xF, true));
}
__device__ __forceinline__ f32x2 swap2(f32x2 v) {
    f32x2 r; r[0] = swap1(v[0]); r[1] = swap1(v[1]); return r;
}

// ---- prep_all: 744 blocks x 256 threads (r12, unchanged) ----
__global__ __launch_bounds__(256) void prep_all(const float* __restrict__ x,
                                                const float* __restrict__ cw,
                                                _Float16* __restrict__ xt,
                                                _Float16* __restrict__ wh2) {
    __shared__ _Float16 lds[272 * 136];   // 73,984 B (interior blocks only)
    const int t   = threadIdx.x;
    const int bid = blockIdx.x;

    if (bid < 256) {
        const int b  = bid >> 7;
        const int z  = (bid >> 2) & 31;
        const int y0 = (bid & 3) << 3;
        {
            const int rw = t >> 4, u = t & 15;
            const int y = rw >> 1, wp = (rw & 1) * 33;
            *(half8*)&lds[(y * 34 + wp) * 136 + u * 8] = (half8)(_Float16)0.f;
        }
        const float* xb = x + (size_t)b * 4194304 + z * 1024 + y0 * 32;
        #pragma unroll 4
        for (int i = 0; i < 32; i++) {
            const int idx4 = i * 256 + t;          // 0..8191
            const int ch = idx4 >> 6;              // 0..127
            const int y  = (idx4 >> 3) & 7;
            const int w4 = idx4 & 7;
            const f32x4 v = *(const f32x4*)(xb + (size_t)ch * 32768 + y * 32 + w4 * 4);
            const int rbase = y * 34 + w4 * 4 + 1;
            #pragma unroll
            for (int e = 0; e < 4; e++)
                lds[(rbase + e) * 136 + ch] = (_Float16)v[e];
        }
        __syncthreads();
        _Float16* dst = xt + ((size_t)((b * 34 + z + 1) * 34 + y0 + 1)) * 34 * 128;
        #pragma unroll
        for (int k = 0; k < 17; k++) {
            const int idx = k * 256 + t;
            const int vox = idx >> 4, u = idx & 15;
            *(half8*)(dst + (size_t)vox * 128 + u * 8) =
                *(const half8*)&lds[vox * 136 + u * 8];
        }
        return;
    }
    if (bid < 520) {
        const int rid = bid - 256;
        const int b = rid / 132, rr = rid - b * 132;
        int zp, yp;
        if (rr < 68) { zp = (rr >= 34) ? 33 : 0; yp = rr % 34; }
        else { const int r2 = rr - 68; zp = 1 + (r2 >> 1); yp = (r2 & 1) ? 33 : 0; }
        _Float16* dst = xt + ((size_t)((b * 34 + zp) * 34 + yp)) * 34 * 128;
        const half8 z8 = (half8)(_Float16)0.f;
        for (int idx = t; idx < 544; idx += 256)
            *(half8*)(dst + idx * 8) = z8;
        return;
    }
    {
        const int idx = (bid - 520) * 256 + t;
        const int n   = idx / 448;
        const int rem = idx - n * 448;
        const int c   = rem >> 5;
        const int k   = rem & 31;
        const int tp  = k >> 4, ca = k & 15;
        const int tap = 2 * c + tp;
        float v = (tap < 27) ? cw[n * 432 + ca * 27 + tap] : 0.0f;
        wh2[c * 4096 + n * 32 + k] = (_Float16)v;
    }
}

// =================== fused caps kernel =========================================
__global__ __launch_bounds__(512, 4) void caps_mfma_kernel(
    const _Float16* __restrict__ xt,  // (2,34,34,34,128) f16 padded
    const _Float16* __restrict__ wh2, // (14,128,32) f16 reordered
    const float* __restrict__ cb,     // (128,)
    const float* __restrict__ bias,   // (8,16)
    float* __restrict__ out)          // (2,8,16,32,32,32) f32
{
    // 78,848 B: slab = 306 live rows + 2 phantom, x 256B.
    // Votes (66,048B) overlay slab after B1; RT(2304 f32)+LG(2304 f32) after B3.
    __shared__ half8 slabv[4928];
    char* smem = (char*)slabv;
    _Float16* Vh = (_Float16*)slabv;
    float* RT = (float*)slabv;
    float* LG = (float*)slabv + 2304;

    const int t  = threadIdx.x;
    const int bx = blockIdx.x;
    const int gid = ((bx & 7) << 8) | (bx >> 3);   // XCD-contiguous (2048 = 8*256)
    const int h = gid & 31;
    const int d = (gid >> 5) & 31;
    const int b = gid >> 10;

    const int wid = t >> 6, lane = t & 63;

    // stage slab: 308 rows x 256B via global_load_lds
    {
        const int lrow = lane >> 4;
        const int s    = lane & 15;
        const int bzd  = b * 34 + d;
        for (int i = wid; i < 77; i += 8) {
            const int rr0 = i << 2;
            const int rr  = rr0 + lrow;
            int zy = rr / 34;
            int j  = rr - zy * 34;
            if (rr >= 306) { zy = 0; j = 0; }
            const int dz  = (zy * 11) >> 5;
            const int dy  = zy - dz * 3;
            const int uu  = s ^ (j & 15);
            const unsigned off =
                ((((unsigned)(bzd + dz) * 34u + (unsigned)(h + dy)) * 34u
                  + (unsigned)j) << 8) + (unsigned)(uu << 4);
            gload_lds16((const char*)xt + off, smem + (rr0 << 8));
        }
    }

    // GEMM setup (swapped operands, r11/r13-verified): D row = ch, D col = voxel.
    const int q = lane >> 4, r = lane & 15;
    const int qlow = q & 1, tphase = q >> 1;

    int zyA[14], dxA[14];
    #pragma unroll
    for (int c = 0; c < 14; c++) {
        int tap = 2 * c + tphase;
        if (tap > 26) tap = 0;             // tap27: weight k-slots are zero
        const int dz = tap / 9, r9 = tap - dz * 9;
        const int dy = r9 / 3,  dxx = r9 - dy * 3;
        zyA[c] = dz * 3 + dy;
        dxA[c] = dxx;
    }
    const int uA = wid * 2 + qlow;
    const _Float16* bp0 = wh2 + r * 32 + q * 8;
    const _Float16* bp1 = bp0 + 2048;

    // chunk-0 B loads issued BEFORE the barrier: latency hides under the drain.
    half8 bf[8];
    #pragma unroll
    for (int nt = 0; nt < 4; nt++) {
        bf[nt]     = *(const half8*)(bp0 + nt * 512);
        bf[nt + 4] = *(const half8*)(bp1 + nt * 512);
    }

    __syncthreads();   // B0: slab staged (drains vmcnt -> bf resident too)

    f32x4 acc[2][8];                       // [vt voxel-half][nt channel-tile]
    #pragma unroll
    for (int i = 0; i < 2; i++)
        #pragma unroll
        for (int j = 0; j < 8; j++) acc[i][j] = (f32x4)0.f;

    #pragma unroll
    for (int c = 0; c < 14; c++) {
        const int jw = r + dxA[c];
        const int js = jw & 15;
        const char* abase = smem + zyA[c] * 8704 + jw * 256 + ((uA ^ js) << 4);
        const half8 af0 = *(const half8*)abase;
        const half8 af1 = *(const half8*)(abase + 4096);
        #pragma unroll
        for (int nt = 0; nt < 8; nt++) {
            const half8 bcur = bf[nt];
            if (c < 13) {   // rotate: prefetch chunk c+1's fragment into same slot
                const _Float16* bp = ((nt < 4) ? bp0 : bp1)
                                     + (c + 1) * 4096 + (nt & 3) * 512;
                bf[nt] = *(const half8*)bp;
            }
            acc[0][nt] = __builtin_amdgcn_mfma_f32_16x16x32_f16(bcur, af0,
                                                                acc[0][nt], 0, 0, 0);
            acc[1][nt] = __builtin_amdgcn_mfma_f32_16x16x32_f16(bcur, af1,
                                                                acc[1][nt], 0, 0, 0);
        }
    }

    __syncthreads();   // B1: slab reads done -> votes overlay

    // epilogue (r13-proven): 4 contiguous channels per fragment -> ds_write_b64
    f32x4 cbq[8];
    #pragma unroll
    for (int nt = 0; nt < 8; nt++)
        cbq[nt] = *(const f32x4*)&cb[nt * 16 + q * 4];
    #pragma unroll
    for (int vt = 0; vt < 2; vt++) {
        _Float16* vp = &Vh[(vt * 16 + r) * 1032 + wid * 128 + q * 4];
        #pragma unroll
        for (int nt = 0; nt < 8; nt++) {
            half4 hv;
            #pragma unroll
            for (int e = 0; e < 4; e++)
                hv[e] = (_Float16)(acc[vt][nt][e] + cbq[nt][e]);
            *(half4*)(vp + nt * 16) = hv;
        }
    }
    __syncthreads();   // B2: vote writes visible

    // routing: 512 threads = 256 (v,o) pairs x 2 in_dim-halves (r12 exact)
    const int p = t >> 1, half = t & 1;
    const int vv = p & 31, oo = p >> 5;
    const int ib = half << 2;
    f32x2 vf2[4][8];
    #pragma unroll
    for (int ii = 0; ii < 4; ii++) {
        #pragma unroll
        for (int ah = 0; ah < 2; ah++) {
            const half8 hv =
                *(const half8*)&Vh[vv * 1032 + (ib + ii) * 128 + oo * 16 + ah * 8];
            #pragma unroll
            for (int k = 0; k < 4; k++) {
                f32x2 e; e[0] = (float)hv[2 * k]; e[1] = (float)hv[2 * k + 1];
                vf2[ii][ah * 4 + k] = e;
            }
        }
    }
    __syncthreads();   // B3: vote reads done -> RT/LG overlay

    float vn[4];
    #pragma unroll
    for (int ii = 0; ii < 4; ii++) {
        f32x2 s = (f32x2)0.f;
        #pragma unroll
        for (int k = 0; k < 8; k++)
            s = __builtin_elementwise_fma(vf2[ii][k], vf2[ii][k], s);
        vn[ii] = sqrtf(s[0] + s[1]);
    }
    f32x2 bl2[8];
    #pragma unroll
    for (int k = 0; k < 8; k++)
        bl2[k] = *(const f32x2*)&bias[oo * 16 + 2 * k];
    float rt[4], lgr[4];
    #pragma unroll
    for (int ii = 0; ii < 4; ii++) { rt[ii] = 0.125f; lgr[ii] = 0.f; }
    f32x2 pre2[8];
    for (int it = 0; it < 3; it++) {
        #pragma unroll
        for (int k = 0; k < 8; k++) pre2[k] = (f32x2)0.f;
        #pragma unroll
        for (int ii = 0; ii < 4; ii++) {
            f32x2 rtv; rtv[0] = rt[ii]; rtv[1] = rt[ii];
            #pragma unroll
            for (int k = 0; k < 8; k++)
                pre2[k] = __builtin_elementwise_fma(rtv, vf2[ii][k], pre2[k]);
        }
        #pragma unroll
        for (int k = 0; k < 8; k++)
            pre2[k] = bl2[k] + pre2[k] + swap2(pre2[k]);
        if (it == 2) break;
        f32x2 s2v = (f32x2)0.f;
        #pragma unroll
        for (int k = 0; k < 8; k++)
            s2v = __builtin_elementwise_fma(pre2[k], pre2[k], s2v);
        const float pn = sqrtf(s2v[0] + s2v[1]);
        #pragma unroll
        for (int ii = 0; ii < 4; ii++) {
            f32x2 dv = (f32x2)0.f;
            #pragma unroll
            for (int k = 0; k < 8; k++)
                dv = __builtin_elementwise_fma(pre2[k], vf2[ii][k], dv);
            lgr[ii] += __fdividef(dv[0] + dv[1], fmaxf(pn * vn[ii], 1e-8f));
            LG[vv * 72 + (ib + ii) * 8 + oo] = lgr[ii];
        }
        __syncthreads();
        {
            const f32x4 E = *(const f32x4*)&LG[vv * 72 + oo * 8 + half * 4];
            f32x4 exv; float ps = 0.f;
            #pragma unroll
            for (int k = 0; k < 4; k++) { exv[k] = __expf(E[k]); ps += exv[k]; }
            const float sum = ps + swap1(ps);
            const float rs = __fdividef(1.f, sum);
            f32x4 w4;
            #pragma unroll
            for (int k = 0; k < 4; k++) w4[k] = exv[k] * rs;
            *(f32x4*)&RT[vv * 72 + oo * 8 + half * 4] = w4;
        }
        __syncthreads();
        #pragma unroll
        for (int ii = 0; ii < 4; ii++)
            rt[ii] = RT[vv * 72 + (ib + ii) * 8 + oo];
    }
    f32x2 s2v = (f32x2)0.f;
    #pragma unroll
    for (int k = 0; k < 8; k++)
        s2v = __builtin_elementwise_fma(pre2[k], pre2[k], s2v);
    const float n2 = s2v[0] + s2v[1];
    const float nn = sqrtf(n2);
    const float scale = __fdividef(n2, (1.f + n2) * (nn + 1e-12f));
    const size_t sp = (size_t)d * 1024 + h * 32 + vv;
    #pragma unroll
    for (int a = 0; a < 8; a++) {
        const float vlo = pre2[(a >> 1)][a & 1];
        const float vhi = pre2[4 + (a >> 1)][a & 1];
        const float pv  = half ? vhi : vlo;
        out[((size_t)((b * 8 + oo) * 16 + half * 8 + a)) * 32768 + sp] = pv * scale;
    }
}

extern "C" void kernel_launch(void* const* d_in, const int* in_sizes, int n_in,
                              void* d_out, int out_size, void* d_ws, size_t ws_size,
                              hipStream_t stream) {
    const float* x    = (const float*)d_in[0];
    const float* cw   = (const float*)d_in[1];
    const float* cb   = (const float*)d_in[2];
    const float* bias = (const float*)d_in[3];
    float* out = (float*)d_out;
    _Float16* wh2 = (_Float16*)d_ws;                     // 114,688 B
    _Float16* xt  = (_Float16*)((char*)d_ws + 114688);   // 20,123,648 B

    hipLaunchKernelGGL(prep_all, dim3(744), dim3(256), 0, stream, x, cw, xt, wh2);
    hipLaunchKernelGGL(caps_mfma_kernel, dim3(2048), dim3(512), 0, stream,
                       xt, wh2, cb, bias, out);
}

// Round 11
// 216.287 us; speedup vs baseline: 1.3795x; 1.3795x over previous
//
#include <hip/hip_runtime.h>
#include <math.h>

// ConvSlimCapsule3D, round 15: REVERT to r12 (best, 212.5us) + ONE isolated change:
// r13's swapped-MFMA epilogue (proven: bank conflicts 4.78M -> 2.69M cycles).
// r14's bf-rotation spilled to scratch (WRITE 76->380MB) -> removed entirely.
// r13's routing remap + OF bounce regressed HBM traffic -> not included.
// prep_all unchanged from r12 (passed, ~9us).

typedef _Float16 half8 __attribute__((ext_vector_type(8)));
typedef _Float16 half4 __attribute__((ext_vector_type(4)));
typedef float f32x4 __attribute__((ext_vector_type(4)));
typedef float f32x2 __attribute__((ext_vector_type(2)));

__device__ __forceinline__ void gload_lds16(const void* g, void* l) {
    __builtin_amdgcn_global_load_lds(
        (const __attribute__((address_space(1))) void*)g,
        (__attribute__((address_space(3))) void*)l, 16, 0, 0);
}

// lane^1 exchange on the VALU (DPP quad_perm(1,0,3,2)).
__device__ __forceinline__ float swap1(float x) {
    return __builtin_bit_cast(float, __builtin_amdgcn_update_dpp(
        0, __builtin_bit_cast(int, x), 0xB1, 0xF, 0xF, true));
}
__device__ __forceinline__ f32x2 swap2(f32x2 v) {
    f32x2 r; r[0] = swap1(v[0]); r[1] = swap1(v[1]); return r;
}

// ---- prep_all: 744 blocks x 256 threads (r12, unchanged) ----
__global__ __launch_bounds__(256) void prep_all(const float* __restrict__ x,
                                                const float* __restrict__ cw,
                                                _Float16* __restrict__ xt,
                                                _Float16* __restrict__ wh2) {
    __shared__ _Float16 lds[272 * 136];   // 73,984 B (interior blocks only)
    const int t   = threadIdx.x;
    const int bid = blockIdx.x;

    if (bid < 256) {
        const int b  = bid >> 7;
        const int z  = (bid >> 2) & 31;
        const int y0 = (bid & 3) << 3;
        {
            const int rw = t >> 4, u = t & 15;
            const int y = rw >> 1, wp = (rw & 1) * 33;
            *(half8*)&lds[(y * 34 + wp) * 136 + u * 8] = (half8)(_Float16)0.f;
        }
        const float* xb = x + (size_t)b * 4194304 + z * 1024 + y0 * 32;
        #pragma unroll 4
        for (int i = 0; i < 32; i++) {
            const int idx4 = i * 256 + t;          // 0..8191
            const int ch = idx4 >> 6;              // 0..127
            const int y  = (idx4 >> 3) & 7;
            const int w4 = idx4 & 7;
            const f32x4 v = *(const f32x4*)(xb + (size_t)ch * 32768 + y * 32 + w4 * 4);
            const int rbase = y * 34 + w4 * 4 + 1;
            #pragma unroll
            for (int e = 0; e < 4; e++)
                lds[(rbase + e) * 136 + ch] = (_Float16)v[e];
        }
        __syncthreads();
        _Float16* dst = xt + ((size_t)((b * 34 + z + 1) * 34 + y0 + 1)) * 34 * 128;
        #pragma unroll
        for (int k = 0; k < 17; k++) {
            const int idx = k * 256 + t;
            const int vox = idx >> 4, u = idx & 15;
            *(half8*)(dst + (size_t)vox * 128 + u * 8) =
                *(const half8*)&lds[vox * 136 + u * 8];
        }
        return;
    }
    if (bid < 520) {
        const int rid = bid - 256;
        const int b = rid / 132, rr = rid - b * 132;
        int zp, yp;
        if (rr < 68) { zp = (rr >= 34) ? 33 : 0; yp = rr % 34; }
        else { const int r2 = rr - 68; zp = 1 + (r2 >> 1); yp = (r2 & 1) ? 33 : 0; }
        _Float16* dst = xt + ((size_t)((b * 34 + zp) * 34 + yp)) * 34 * 128;
        const half8 z8 = (half8)(_Float16)0.f;
        for (int idx = t; idx < 544; idx += 256)
            *(half8*)(dst + idx * 8) = z8;
        return;
    }
    {
        const int idx = (bid - 520) * 256 + t;
        const int n   = idx / 448;
        const int rem = idx - n * 448;
        const int c   = rem >> 5;
        const int k   = rem & 31;
        const int tp  = k >> 4, ca = k & 15;
        const int tap = 2 * c + tp;
        float v = (tap < 27) ? cw[n * 432 + ca * 27 + tap] : 0.0f;
        wh2[c * 4096 + n * 32 + k] = (_Float16)v;
    }
}

// =================== fused caps kernel =========================================
__global__ __launch_bounds__(512, 4) void caps_mfma_kernel(
    const _Float16* __restrict__ xt,  // (2,34,34,34,128) f16 padded
    const _Float16* __restrict__ wh2, // (14,128,32) f16 reordered
    const float* __restrict__ cb,     // (128,)
    const float* __restrict__ bias,   // (8,16)
    float* __restrict__ out)          // (2,8,16,32,32,32) f32
{
    // 78,848 B: slab = 306 live rows + 2 phantom, x 256B.
    // Votes (66,048B) overlay slab after B1; RT(2304 f32)+LG(2304 f32) after B3.
    __shared__ half8 slabv[4928];
    char* smem = (char*)slabv;
    _Float16* Vh = (_Float16*)slabv;
    float* RT = (float*)slabv;
    float* LG = (float*)slabv + 2304;

    const int t  = threadIdx.x;
    const int bx = blockIdx.x;
    const int gid = ((bx & 7) << 8) | (bx >> 3);   // XCD-contiguous (2048 = 8*256)
    const int h = gid & 31;
    const int d = (gid >> 5) & 31;
    const int b = gid >> 10;

    const int wid = t >> 6, lane = t & 63;

    // stage slab: 308 rows x 256B via global_load_lds
    {
        const int lrow = lane >> 4;
        const int s    = lane & 15;
        const int bzd  = b * 34 + d;
        for (int i = wid; i < 77; i += 8) {
            const int rr0 = i << 2;
            const int rr  = rr0 + lrow;
            int zy = rr / 34;
            int j  = rr - zy * 34;
            if (rr >= 306) { zy = 0; j = 0; }
            const int dz  = (zy * 11) >> 5;
            const int dy  = zy - dz * 3;
            const int uu  = s ^ (j & 15);
            const unsigned off =
                ((((unsigned)(bzd + dz) * 34u + (unsigned)(h + dy)) * 34u
                  + (unsigned)j) << 8) + (unsigned)(uu << 4);
            gload_lds16((const char*)xt + off, smem + (rr0 << 8));
        }
    }
    __syncthreads();   // B0: slab staged

    // GEMM (swapped operands, r11/r13-verified): D row = ch, D col = voxel.
    const int q = lane >> 4, r = lane & 15;
    const int qlow = q & 1, tphase = q >> 1;

    int zyA[14], dxA[14];
    #pragma unroll
    for (int c = 0; c < 14; c++) {
        int tap = 2 * c + tphase;
        if (tap > 26) tap = 0;             // tap27: weight k-slots are zero
        const int dz = tap / 9, r9 = tap - dz * 9;
        const int dy = r9 / 3,  dxx = r9 - dy * 3;
        zyA[c] = dz * 3 + dy;
        dxA[c] = dxx;
    }
    const int uA = wid * 2 + qlow;
    const _Float16* bp0 = wh2 + r * 32 + q * 8;
    const _Float16* bp1 = bp0 + 2048;

    f32x4 acc[2][8];                       // [vt voxel-half][nt channel-tile]
    #pragma unroll
    for (int i = 0; i < 2; i++)
        #pragma unroll
        for (int j = 0; j < 8; j++) acc[i][j] = (f32x4)0.f;

    #pragma unroll
    for (int c = 0; c < 14; c++) {
        half8 bf[8];
        #pragma unroll
        for (int nt = 0; nt < 4; nt++) {
            bf[nt]     = *(const half8*)(bp0 + c * 4096 + nt * 512);
            bf[nt + 4] = *(const half8*)(bp1 + c * 4096 + nt * 512);
        }
        const int jw = r + dxA[c];
        const int js = jw & 15;
        const char* abase = smem + zyA[c] * 8704 + jw * 256 + ((uA ^ js) << 4);
        const half8 af0 = *(const half8*)abase;
        const half8 af1 = *(const half8*)(abase + 4096);
        #pragma unroll
        for (int nt = 0; nt < 8; nt++) {
            acc[0][nt] = __builtin_amdgcn_mfma_f32_16x16x32_f16(bf[nt], af0,
                                                                acc[0][nt], 0, 0, 0);
            acc[1][nt] = __builtin_amdgcn_mfma_f32_16x16x32_f16(bf[nt], af1,
                                                                acc[1][nt], 0, 0, 0);
        }
    }

    __syncthreads();   // B1: slab reads done -> votes overlay

    // epilogue (r13-proven): 4 contiguous channels per fragment -> ds_write_b64
    f32x4 cbq[8];
    #pragma unroll
    for (int nt = 0; nt < 8; nt++)
        cbq[nt] = *(const f32x4*)&cb[nt * 16 + q * 4];
    #pragma unroll
    for (int vt = 0; vt < 2; vt++) {
        _Float16* vp = &Vh[(vt * 16 + r) * 1032 + wid * 128 + q * 4];
        #pragma unroll
        for (int nt = 0; nt < 8; nt++) {
            half4 hv;
            #pragma unroll
            for (int e = 0; e < 4; e++)
                hv[e] = (_Float16)(acc[vt][nt][e] + cbq[nt][e]);
            *(half4*)(vp + nt * 16) = hv;
        }
    }
    __syncthreads();   // B2: vote writes visible

    // routing: 512 threads = 256 (v,o) pairs x 2 in_dim-halves (r12 exact)
    const int p = t >> 1, half = t & 1;
    const int vv = p & 31, oo = p >> 5;
    const int ib = half << 2;
    f32x2 vf2[4][8];
    #pragma unroll
    for (int ii = 0; ii < 4; ii++) {
        #pragma unroll
        for (int ah = 0; ah < 2; ah++) {
            const half8 hv =
                *(const half8*)&Vh[vv * 1032 + (ib + ii) * 128 + oo * 16 + ah * 8];
            #pragma unroll
            for (int k = 0; k < 4; k++) {
                f32x2 e; e[0] = (float)hv[2 * k]; e[1] = (float)hv[2 * k + 1];
                vf2[ii][ah * 4 + k] = e;
            }
        }
    }
    __syncthreads();   // B3: vote reads done -> RT/LG overlay

    float vn[4];
    #pragma unroll
    for (int ii = 0; ii < 4; ii++) {
        f32x2 s = (f32x2)0.f;
        #pragma unroll
        for (int k = 0; k < 8; k++)
            s = __builtin_elementwise_fma(vf2[ii][k], vf2[ii][k], s);
        vn[ii] = sqrtf(s[0] + s[1]);
    }
    f32x2 bl2[8];
    #pragma unroll
    for (int k = 0; k < 8; k++)
        bl2[k] = *(const f32x2*)&bias[oo * 16 + 2 * k];
    float rt[4], lgr[4];
    #pragma unroll
    for (int ii = 0; ii < 4; ii++) { rt[ii] = 0.125f; lgr[ii] = 0.f; }
    f32x2 pre2[8];
    for (int it = 0; it < 3; it++) {
        #pragma unroll
        for (int k = 0; k < 8; k++) pre2[k] = (f32x2)0.f;
        #pragma unroll
        for (int ii = 0; ii < 4; ii++) {
            f32x2 rtv; rtv[0] = rt[ii]; rtv[1] = rt[ii];
            #pragma unroll
            for (int k = 0; k < 8; k++)
                pre2[k] = __builtin_elementwise_fma(rtv, vf2[ii][k], pre2[k]);
        }
        #pragma unroll
        for (int k = 0; k < 8; k++)
            pre2[k] = bl2[k] + pre2[k] + swap2(pre2[k]);
        if (it == 2) break;
        f32x2 s2v = (f32x2)0.f;
        #pragma unroll
        for (int k = 0; k < 8; k++)
            s2v = __builtin_elementwise_fma(pre2[k], pre2[k], s2v);
        const float pn = sqrtf(s2v[0] + s2v[1]);
        #pragma unroll
        for (int ii = 0; ii < 4; ii++) {
            f32x2 dv = (f32x2)0.f;
            #pragma unroll
            for (int k = 0; k < 8; k++)
                dv = __builtin_elementwise_fma(pre2[k], vf2[ii][k], dv);
            lgr[ii] += __fdividef(dv[0] + dv[1], fmaxf(pn * vn[ii], 1e-8f));
            LG[vv * 72 + (ib + ii) * 8 + oo] = lgr[ii];
        }
        __syncthreads();
        {
            const f32x4 E = *(const f32x4*)&LG[vv * 72 + oo * 8 + half * 4];
            f32x4 exv; float ps = 0.f;
            #pragma unroll
            for (int k = 0; k < 4; k++) { exv[k] = __expf(E[k]); ps += exv[k]; }
            const float sum = ps + swap1(ps);
            const float rs = __fdividef(1.f, sum);
            f32x4 w4;
            #pragma unroll
            for (int k = 0; k < 4; k++) w4[k] = exv[k] * rs;
            *(f32x4*)&RT[vv * 72 + oo * 8 + half * 4] = w4;
        }
        __syncthreads();
        #pragma unroll
        for (int ii = 0; ii < 4; ii++)
            rt[ii] = RT[vv * 72 + (ib + ii) * 8 + oo];
    }
    f32x2 s2v = (f32x2)0.f;
    #pragma unroll
    for (int k = 0; k < 8; k++)
        s2v = __builtin_elementwise_fma(pre2[k], pre2[k], s2v);
    const float n2 = s2v[0] + s2v[1];
    const float nn = sqrtf(n2);
    const float scale = __fdividef(n2, (1.f + n2) * (nn + 1e-12f));
    const size_t sp = (size_t)d * 1024 + h * 32 + vv;
    #pragma unroll
    for (int a = 0; a < 8; a++) {
        const float vlo = pre2[(a >> 1)][a & 1];
        const float vhi = pre2[4 + (a >> 1)][a & 1];
        const float pv  = half ? vhi : vlo;
        out[((size_t)((b * 8 + oo) * 16 + half * 8 + a)) * 32768 + sp] = pv * scale;
    }
}

extern "C" void kernel_launch(void* const* d_in, const int* in_sizes, int n_in,
                              void* d_out, int out_size, void* d_ws, size_t ws_size,
                              hipStream_t stream) {
    const float* x    = (const float*)d_in[0];
    const float* cw   = (const float*)d_in[1];
    const float* cb   = (const float*)d_in[2];
    const float* bias = (const float*)d_in[3];
    float* out = (float*)d_out;
    _Float16* wh2 = (_Float16*)d_ws;                     // 114,688 B
    _Float16* xt  = (_Float16*)((char*)d_ws + 114688);   // 20,123,648 B

    hipLaunchKernelGGL(prep_all, dim3(744), dim3(256), 0, stream, x, cw, xt, wh2);
    hipLaunchKernelGGL(caps_mfma_kernel, dim3(2048), dim3(512), 0, stream,
                       xt, wh2, cb, bias, out);
}

// Round 12
// 182.692 us; speedup vs baseline: 1.6332x; 1.1839x over previous
//
#include <hip/hip_runtime.h>
#include <math.h>

// ConvSlimCapsule3D, round 16: r15 base + B-load deduplication.
// Diagnosis: bf[nt] depends only on (r,q,nt,c) -> all 8 waves loaded IDENTICAL
// B-fragments (64 redundant 1KB L1 loads per block per chunk; ~48us/CU of L1 path,
// the largest convoy term). Fix: wave wid -> (idp=wid>>1, chh=wid&1) computes
// 2 in_dims x 64 ch x 32 vox: bf loads/wave 8->4 (block-wide 64->32), af ds_reads
// 2->4, MFMA count unchanged, acc unchanged (64 regs), peak live regs LOWER.
// Epilogue (r11/r15-verified D-layout), routing (r12 exact), prep_all unchanged.

typedef _Float16 half8 __attribute__((ext_vector_type(8)));
typedef _Float16 half4 __attribute__((ext_vector_type(4)));
typedef float f32x4 __attribute__((ext_vector_type(4)));
typedef float f32x2 __attribute__((ext_vector_type(2)));

__device__ __forceinline__ void gload_lds16(const void* g, void* l) {
    __builtin_amdgcn_global_load_lds(
        (const __attribute__((address_space(1))) void*)g,
        (__attribute__((address_space(3))) void*)l, 16, 0, 0);
}

// lane^1 exchange on the VALU (DPP quad_perm(1,0,3,2)).
__device__ __forceinline__ float swap1(float x) {
    return __builtin_bit_cast(float, __builtin_amdgcn_update_dpp(
        0, __builtin_bit_cast(int, x), 0xB1, 0xF, 0xF, true));
}
__device__ __forceinline__ f32x2 swap2(f32x2 v) {
    f32x2 r; r[0] = swap1(v[0]); r[1] = swap1(v[1]); return r;
}

// ---- prep_all: 744 blocks x 256 threads (r12, unchanged) ----
__global__ __launch_bounds__(256) void prep_all(const float* __restrict__ x,
                                                const float* __restrict__ cw,
                                                _Float16* __restrict__ xt,
                                                _Float16* __restrict__ wh2) {
    __shared__ _Float16 lds[272 * 136];   // 73,984 B (interior blocks only)
    const int t   = threadIdx.x;
    const int bid = blockIdx.x;

    if (bid < 256) {
        const int b  = bid >> 7;
        const int z  = (bid >> 2) & 31;
        const int y0 = (bid & 3) << 3;
        {
            const int rw = t >> 4, u = t & 15;
            const int y = rw >> 1, wp = (rw & 1) * 33;
            *(half8*)&lds[(y * 34 + wp) * 136 + u * 8] = (half8)(_Float16)0.f;
        }
        const float* xb = x + (size_t)b * 4194304 + z * 1024 + y0 * 32;
        #pragma unroll 4
        for (int i = 0; i < 32; i++) {
            const int idx4 = i * 256 + t;          // 0..8191
            const int ch = idx4 >> 6;              // 0..127
            const int y  = (idx4 >> 3) & 7;
            const int w4 = idx4 & 7;
            const f32x4 v = *(const f32x4*)(xb + (size_t)ch * 32768 + y * 32 + w4 * 4);
            const int rbase = y * 34 + w4 * 4 + 1;
            #pragma unroll
            for (int e = 0; e < 4; e++)
                lds[(rbase + e) * 136 + ch] = (_Float16)v[e];
        }
        __syncthreads();
        _Float16* dst = xt + ((size_t)((b * 34 + z + 1) * 34 + y0 + 1)) * 34 * 128;
        #pragma unroll
        for (int k = 0; k < 17; k++) {
            const int idx = k * 256 + t;
            const int vox = idx >> 4, u = idx & 15;
            *(half8*)(dst + (size_t)vox * 128 + u * 8) =
                *(const half8*)&lds[vox * 136 + u * 8];
        }
        return;
    }
    if (bid < 520) {
        const int rid = bid - 256;
        const int b = rid / 132, rr = rid - b * 132;
        int zp, yp;
        if (rr < 68) { zp = (rr >= 34) ? 33 : 0; yp = rr % 34; }
        else { const int r2 = rr - 68; zp = 1 + (r2 >> 1); yp = (r2 & 1) ? 33 : 0; }
        _Float16* dst = xt + ((size_t)((b * 34 + zp) * 34 + yp)) * 34 * 128;
        const half8 z8 = (half8)(_Float16)0.f;
        for (int idx = t; idx < 544; idx += 256)
            *(half8*)(dst + idx * 8) = z8;
        return;
    }
    {
        const int idx = (bid - 520) * 256 + t;
        const int n   = idx / 448;
        const int rem = idx - n * 448;
        const int c   = rem >> 5;
        const int k   = rem & 31;
        const int tp  = k >> 4, ca = k & 15;
        const int tap = 2 * c + tp;
        float v = (tap < 27) ? cw[n * 432 + ca * 27 + tap] : 0.0f;
        wh2[c * 4096 + n * 32 + k] = (_Float16)v;
    }
}

// =================== fused caps kernel =========================================
__global__ __launch_bounds__(512, 4) void caps_mfma_kernel(
    const _Float16* __restrict__ xt,  // (2,34,34,34,128) f16 padded
    const _Float16* __restrict__ wh2, // (14,128,32) f16 reordered
    const float* __restrict__ cb,     // (128,)
    const float* __restrict__ bias,   // (8,16)
    float* __restrict__ out)          // (2,8,16,32,32,32) f32
{
    // 78,848 B: slab = 306 live rows + 2 phantom, x 256B.
    // Votes (66,048B) overlay slab after B1; RT(2304 f32)+LG(2304 f32) after B3.
    __shared__ half8 slabv[4928];
    char* smem = (char*)slabv;
    _Float16* Vh = (_Float16*)slabv;
    float* RT = (float*)slabv;
    float* LG = (float*)slabv + 2304;

    const int t  = threadIdx.x;
    const int bx = blockIdx.x;
    const int gid = ((bx & 7) << 8) | (bx >> 3);   // XCD-contiguous (2048 = 8*256)
    const int h = gid & 31;
    const int d = (gid >> 5) & 31;
    const int b = gid >> 10;

    const int wid = t >> 6, lane = t & 63;

    // stage slab: 308 rows x 256B via global_load_lds
    {
        const int lrow = lane >> 4;
        const int s    = lane & 15;
        const int bzd  = b * 34 + d;
        for (int i = wid; i < 77; i += 8) {
            const int rr0 = i << 2;
            const int rr  = rr0 + lrow;
            int zy = rr / 34;
            int j  = rr - zy * 34;
            if (rr >= 306) { zy = 0; j = 0; }
            const int dz  = (zy * 11) >> 5;
            const int dy  = zy - dz * 3;
            const int uu  = s ^ (j & 15);
            const unsigned off =
                ((((unsigned)(bzd + dz) * 34u + (unsigned)(h + dy)) * 34u
                  + (unsigned)j) << 8) + (unsigned)(uu << 4);
            gload_lds16((const char*)xt + off, smem + (rr0 << 8));
        }
    }
    __syncthreads();   // B0: slab staged

    // GEMM (swapped operands): wave = (idp = wid>>1, chh = wid&1):
    // 2 in_dims (2*idp, 2*idp+1) x 64 channels (chh*64..) x 32 voxels.
    const int q = lane >> 4, r = lane & 15;
    const int qlow = q & 1, tphase = q >> 1;
    const int idp = wid >> 1, chh = wid & 1;

    int zyA[14], dxA[14];
    #pragma unroll
    for (int c = 0; c < 14; c++) {
        int tap = 2 * c + tphase;
        if (tap > 26) tap = 0;             // tap27: weight k-slots are zero
        const int dz = tap / 9, r9 = tap - dz * 9;
        const int dy = r9 / 3,  dxx = r9 - dy * 3;
        zyA[c] = dz * 3 + dy;
        dxA[c] = dxx;
    }
    const int uA0 = 4 * idp + qlow;        // in_dim 2*idp
    const int uA1 = uA0 + 2;               // in_dim 2*idp+1
    const _Float16* bp = wh2 + (chh * 64 + r) * 32 + q * 8;  // + c*4096 + nt*512

    f32x4 acc[2][2][4];                    // [jj in-pair][vt voxel-half][nt ch-tile]
    #pragma unroll
    for (int i = 0; i < 2; i++)
        #pragma unroll
        for (int j = 0; j < 2; j++)
            #pragma unroll
            for (int k = 0; k < 4; k++) acc[i][j][k] = (f32x4)0.f;

    #pragma unroll
    for (int c = 0; c < 14; c++) {
        half8 bf[4];
        #pragma unroll
        for (int nt = 0; nt < 4; nt++)
            bf[nt] = *(const half8*)(bp + c * 4096 + nt * 512);
        const int jw = r + dxA[c];
        const int js = jw & 15;
        const char* abase = smem + zyA[c] * 8704 + jw * 256;
        const char* a0 = abase + ((uA0 ^ js) << 4);
        const char* a1 = abase + ((uA1 ^ js) << 4);
        half8 af[2][2];
        af[0][0] = *(const half8*)a0;             // in_dim 2idp,   vt0
        af[0][1] = *(const half8*)(a0 + 4096);    // in_dim 2idp,   vt1 (+16 rows)
        af[1][0] = *(const half8*)a1;             // in_dim 2idp+1, vt0
        af[1][1] = *(const half8*)(a1 + 4096);    // in_dim 2idp+1, vt1
        #pragma unroll
        for (int jj = 0; jj < 2; jj++)
            #pragma unroll
            for (int vt = 0; vt < 2; vt++)
                #pragma unroll
                for (int nt = 0; nt < 4; nt++)
                    acc[jj][vt][nt] = __builtin_amdgcn_mfma_f32_16x16x32_f16(
                        bf[nt], af[jj][vt], acc[jj][vt][nt], 0, 0, 0);
    }

    __syncthreads();   // B1: slab reads done -> votes overlay

    // epilogue (r11/r15-verified layout): ch = chh*64 + nt*16 + q*4 + e,
    // in_dim = 2*idp + jj, voxel = vt*16 + r. One ds_write_b64 per fragment.
    f32x4 cbq[4];
    #pragma unroll
    for (int nt = 0; nt < 4; nt++)
        cbq[nt] = *(const f32x4*)&cb[chh * 64 + nt * 16 + q * 4];
    #pragma unroll
    for (int jj = 0; jj < 2; jj++) {
        #pragma unroll
        for (int vt = 0; vt < 2; vt++) {
            _Float16* vp = &Vh[(vt * 16 + r) * 1032 + (2 * idp + jj) * 128
                               + chh * 64 + q * 4];
            #pragma unroll
            for (int nt = 0; nt < 4; nt++) {
                half4 hv;
                #pragma unroll
                for (int e = 0; e < 4; e++)
                    hv[e] = (_Float16)(acc[jj][vt][nt][e] + cbq[nt][e]);
                *(half4*)(vp + nt * 16) = hv;
            }
        }
    }
    __syncthreads();   // B2: vote writes visible

    // routing: 512 threads = 256 (v,o) pairs x 2 in_dim-halves (r12 exact)
    const int p = t >> 1, half = t & 1;
    const int vv = p & 31, oo = p >> 5;
    const int ib = half << 2;
    f32x2 vf2[4][8];
    #pragma unroll
    for (int ii = 0; ii < 4; ii++) {
        #pragma unroll
        for (int ah = 0; ah < 2; ah++) {
            const half8 hv =
                *(const half8*)&Vh[vv * 1032 + (ib + ii) * 128 + oo * 16 + ah * 8];
            #pragma unroll
            for (int k = 0; k < 4; k++) {
                f32x2 e; e[0] = (float)hv[2 * k]; e[1] = (float)hv[2 * k + 1];
                vf2[ii][ah * 4 + k] = e;
            }
        }
    }
    __syncthreads();   // B3: vote reads done -> RT/LG overlay

    float vn[4];
    #pragma unroll
    for (int ii = 0; ii < 4; ii++) {
        f32x2 s = (f32x2)0.f;
        #pragma unroll
        for (int k = 0; k < 8; k++)
            s = __builtin_elementwise_fma(vf2[ii][k], vf2[ii][k], s);
        vn[ii] = sqrtf(s[0] + s[1]);
    }
    f32x2 bl2[8];
    #pragma unroll
    for (int k = 0; k < 8; k++)
        bl2[k] = *(const f32x2*)&bias[oo * 16 + 2 * k];
    float rt[4], lgr[4];
    #pragma unroll
    for (int ii = 0; ii < 4; ii++) { rt[ii] = 0.125f; lgr[ii] = 0.f; }
    f32x2 pre2[8];
    for (int it = 0; it < 3; it++) {
        #pragma unroll
        for (int k = 0; k < 8; k++) pre2[k] = (f32x2)0.f;
        #pragma unroll
        for (int ii = 0; ii < 4; ii++) {
            f32x2 rtv; rtv[0] = rt[ii]; rtv[1] = rt[ii];
            #pragma unroll
            for (int k = 0; k < 8; k++)
                pre2[k] = __builtin_elementwise_fma(rtv, vf2[ii][k], pre2[k]);
        }
        #pragma unroll
        for (int k = 0; k < 8; k++)
            pre2[k] = bl2[k] + pre2[k] + swap2(pre2[k]);
        if (it == 2) break;
        f32x2 s2v = (f32x2)0.f;
        #pragma unroll
        for (int k = 0; k < 8; k++)
            s2v = __builtin_elementwise_fma(pre2[k], pre2[k], s2v);
        const float pn = sqrtf(s2v[0] + s2v[1]);
        #pragma unroll
        for (int ii = 0; ii < 4; ii++) {
            f32x2 dv = (f32x2)0.f;
            #pragma unroll
            for (int k = 0; k < 8; k++)
                dv = __builtin_elementwise_fma(pre2[k], vf2[ii][k], dv);
            lgr[ii] += __fdividef(dv[0] + dv[1], fmaxf(pn * vn[ii], 1e-8f));
            LG[vv * 72 + (ib + ii) * 8 + oo] = lgr[ii];
        }
        __syncthreads();
        {
            const f32x4 E = *(const f32x4*)&LG[vv * 72 + oo * 8 + half * 4];
            f32x4 exv; float ps = 0.f;
            #pragma unroll
            for (int k = 0; k < 4; k++) { exv[k] = __expf(E[k]); ps += exv[k]; }
            const float sum = ps + swap1(ps);
            const float rs = __fdividef(1.f, sum);
            f32x4 w4;
            #pragma unroll
            for (int k = 0; k < 4; k++) w4[k] = exv[k] * rs;
            *(f32x4*)&RT[vv * 72 + oo * 8 + half * 4] = w4;
        }
        __syncthreads();
        #pragma unroll
        for (int ii = 0; ii < 4; ii++)
            rt[ii] = RT[vv * 72 + (ib + ii) * 8 + oo];
    }
    f32x2 s2v = (f32x2)0.f;
    #pragma unroll
    for (int k = 0; k < 8; k++)
        s2v = __builtin_elementwise_fma(pre2[k], pre2[k], s2v);
    const float n2 = s2v[0] + s2v[1];
    const float nn = sqrtf(n2);
    const float scale = __fdividef(n2, (1.f + n2) * (nn + 1e-12f));
    const size_t sp = (size_t)d * 1024 + h * 32 + vv;
    #pragma unroll
    for (int a = 0; a < 8; a++) {
        const float vlo = pre2[(a >> 1)][a & 1];
        const float vhi = pre2[4 + (a >> 1)][a & 1];
        const float pv  = half ? vhi : vlo;
        out[((size_t)((b * 8 + oo) * 16 + half * 8 + a)) * 32768 + sp] = pv * scale;
    }
}

extern "C" void kernel_launch(void* const* d_in, const int* in_sizes, int n_in,
                              void* d_out, int out_size, void* d_ws, size_t ws_size,
                              hipStream_t stream) {
    const float* x    = (const float*)d_in[0];
    const float* cw   = (const float*)d_in[1];
    const float* cb   = (const float*)d_in[2];
    const float* bias = (const float*)d_in[3];
    float* out = (float*)d_out;
    _Float16* wh2 = (_Float16*)d_ws;                     // 114,688 B
    _Float16* xt  = (_Float16*)((char*)d_ws + 114688);   // 20,123,648 B

    hipLaunchKernelGGL(prep_all, dim3(744), dim3(256), 0, stream, x, cw, xt, wh2);
    hipLaunchKernelGGL(caps_mfma_kernel, dim3(2048), dim3(512), 0, stream,
                       xt, wh2, cb, bias, out);
}

// Round 13
// 174.164 us; speedup vs baseline: 1.7132x; 1.0490x over previous
//
#include <hip/hip_runtime.h>
#include <math.h>

// ConvSlimCapsule3D, round 17: r16 base (182.7us total, caps 110us) +
//  - r13's barrier-free DPP routing (HW-verified correct in r13): oo=t&7,
//    half=bit3, vv=t>>4; softmax over o = 8-lane DPP sum8; i-half combine =
//    row_ror:8. Removes 4 barriers + LG/RT LDS round-trips.
//  - FIXED full-line OF readout (r13's regression was 64B half-line stores ->
//    RMW traffic): thread=(ch=idx>>3, sg=idx&7), each instr = 8 planes x 128B
//    full lines, 2 reps.
//  - s_setprio(1) around the MFMA cluster (T5; phase-drifted blocks now exist).
//  - GEMM (B-dedup idp/chh split), epilogue, prep_all unchanged from r16.

typedef _Float16 half8 __attribute__((ext_vector_type(8)));
typedef _Float16 half4 __attribute__((ext_vector_type(4)));
typedef float f32x4 __attribute__((ext_vector_type(4)));
typedef float f32x2 __attribute__((ext_vector_type(2)));

__device__ __forceinline__ void gload_lds16(const void* g, void* l) {
    __builtin_amdgcn_global_load_lds(
        (const __attribute__((address_space(1))) void*)g,
        (__attribute__((address_space(3))) void*)l, 16, 0, 0);
}

template <int CTRL>
__device__ __forceinline__ float dppf(float x) {
    return __builtin_bit_cast(float, __builtin_amdgcn_update_dpp(
        0, __builtin_bit_cast(int, x), CTRL, 0xF, 0xF, true));
}
// sum across each aligned 8-lane group (VALU only; r10/r13-proven trio)
__device__ __forceinline__ float sum8(float x) {
    x += dppf<0xB1>(x);    // quad_perm(1,0,3,2): ^1
    x += dppf<0x4E>(x);    // quad_perm(2,3,0,1): ^2
    x += dppf<0x141>(x);   // row_half_mirror: completes the 8-group
    return x;
}
// lane^8 exchange (row_ror:8 within 16-lane row; r13-proven)
__device__ __forceinline__ float ror8f(float x) { return dppf<0x128>(x); }

// ---- prep_all: 744 blocks x 256 threads (r12, unchanged) ----
__global__ __launch_bounds__(256) void prep_all(const float* __restrict__ x,
                                                const float* __restrict__ cw,
                                                _Float16* __restrict__ xt,
                                                _Float16* __restrict__ wh2) {
    __shared__ _Float16 lds[272 * 136];   // 73,984 B (interior blocks only)
    const int t   = threadIdx.x;
    const int bid = blockIdx.x;

    if (bid < 256) {
        const int b  = bid >> 7;
        const int z  = (bid >> 2) & 31;
        const int y0 = (bid & 3) << 3;
        {
            const int rw = t >> 4, u = t & 15;
            const int y = rw >> 1, wp = (rw & 1) * 33;
            *(half8*)&lds[(y * 34 + wp) * 136 + u * 8] = (half8)(_Float16)0.f;
        }
        const float* xb = x + (size_t)b * 4194304 + z * 1024 + y0 * 32;
        #pragma unroll 4
        for (int i = 0; i < 32; i++) {
            const int idx4 = i * 256 + t;          // 0..8191
            const int ch = idx4 >> 6;              // 0..127
            const int y  = (idx4 >> 3) & 7;
            const int w4 = idx4 & 7;
            const f32x4 v = *(const f32x4*)(xb + (size_t)ch * 32768 + y * 32 + w4 * 4);
            const int rbase = y * 34 + w4 * 4 + 1;
            #pragma unroll
            for (int e = 0; e < 4; e++)
                lds[(rbase + e) * 136 + ch] = (_Float16)v[e];
        }
        __syncthreads();
        _Float16* dst = xt + ((size_t)((b * 34 + z + 1) * 34 + y0 + 1)) * 34 * 128;
        #pragma unroll
        for (int k = 0; k < 17; k++) {
            const int idx = k * 256 + t;
            const int vox = idx >> 4, u = idx & 15;
            *(half8*)(dst + (size_t)vox * 128 + u * 8) =
                *(const half8*)&lds[vox * 136 + u * 8];
        }
        return;
    }
    if (bid < 520) {
        const int rid = bid - 256;
        const int b = rid / 132, rr = rid - b * 132;
        int zp, yp;
        if (rr < 68) { zp = (rr >= 34) ? 33 : 0; yp = rr % 34; }
        else { const int r2 = rr - 68; zp = 1 + (r2 >> 1); yp = (r2 & 1) ? 33 : 0; }
        _Float16* dst = xt + ((size_t)((b * 34 + zp) * 34 + yp)) * 34 * 128;
        const half8 z8 = (half8)(_Float16)0.f;
        for (int idx = t; idx < 544; idx += 256)
            *(half8*)(dst + idx * 8) = z8;
        return;
    }
    {
        const int idx = (bid - 520) * 256 + t;
        const int n   = idx / 448;
        const int rem = idx - n * 448;
        const int c   = rem >> 5;
        const int k   = rem & 31;
        const int tp  = k >> 4, ca = k & 15;
        const int tap = 2 * c + tp;
        float v = (tap < 27) ? cw[n * 432 + ca * 27 + tap] : 0.0f;
        wh2[c * 4096 + n * 32 + k] = (_Float16)v;
    }
}

// =================== fused caps kernel =========================================
__global__ __launch_bounds__(512, 4) void caps_mfma_kernel(
    const _Float16* __restrict__ xt,  // (2,34,34,34,128) f16 padded
    const _Float16* __restrict__ wh2, // (14,128,32) f16 reordered
    const float* __restrict__ cb,     // (128,)
    const float* __restrict__ bias,   // (8,16)
    float* __restrict__ out)          // (2,8,16,32,32,32) f32
{
    // 78,848 B: slab = 306 live rows + 2 phantom, x 256B.
    // Votes (66,048B) overlay slab after B1; OF (32x130 f32) overlays after B3.
    __shared__ half8 slabv[4928];
    char* smem = (char*)slabv;
    _Float16* Vh = (_Float16*)slabv;
    float* OF = (float*)slabv;        // [vox 32][ch, stride 130] f32 = 16,640 B

    const int t  = threadIdx.x;
    const int bx = blockIdx.x;
    const int gid = ((bx & 7) << 8) | (bx >> 3);   // XCD-contiguous (2048 = 8*256)
    const int h = gid & 31;
    const int d = (gid >> 5) & 31;
    const int b = gid >> 10;

    const int wid = t >> 6, lane = t & 63;

    // stage slab: 308 rows x 256B via global_load_lds
    {
        const int lrow = lane >> 4;
        const int s    = lane & 15;
        const int bzd  = b * 34 + d;
        for (int i = wid; i < 77; i += 8) {
            const int rr0 = i << 2;
            const int rr  = rr0 + lrow;
            int zy = rr / 34;
            int j  = rr - zy * 34;
            if (rr >= 306) { zy = 0; j = 0; }
            const int dz  = (zy * 11) >> 5;
            const int dy  = zy - dz * 3;
            const int uu  = s ^ (j & 15);
            const unsigned off =
                ((((unsigned)(bzd + dz) * 34u + (unsigned)(h + dy)) * 34u
                  + (unsigned)j) << 8) + (unsigned)(uu << 4);
            gload_lds16((const char*)xt + off, smem + (rr0 << 8));
        }
    }
    __syncthreads();   // B0: slab staged

    // GEMM (swapped operands, B-dedup): wave = (idp = wid>>1, chh = wid&1):
    // 2 in_dims (2*idp, 2*idp+1) x 64 channels (chh*64..) x 32 voxels.
    const int q = lane >> 4, r = lane & 15;
    const int qlow = q & 1, tphase = q >> 1;
    const int idp = wid >> 1, chh = wid & 1;

    int zyA[14], dxA[14];
    #pragma unroll
    for (int c = 0; c < 14; c++) {
        int tap = 2 * c + tphase;
        if (tap > 26) tap = 0;             // tap27: weight k-slots are zero
        const int dz = tap / 9, r9 = tap - dz * 9;
        const int dy = r9 / 3,  dxx = r9 - dy * 3;
        zyA[c] = dz * 3 + dy;
        dxA[c] = dxx;
    }
    const int uA0 = 4 * idp + qlow;        // in_dim 2*idp
    const int uA1 = uA0 + 2;               // in_dim 2*idp+1
    const _Float16* bp = wh2 + (chh * 64 + r) * 32 + q * 8;  // + c*4096 + nt*512

    f32x4 acc[2][2][4];                    // [jj in-pair][vt voxel-half][nt ch-tile]
    #pragma unroll
    for (int i = 0; i < 2; i++)
        #pragma unroll
        for (int j = 0; j < 2; j++)
            #pragma unroll
            for (int k = 0; k < 4; k++) acc[i][j][k] = (f32x4)0.f;

    #pragma unroll
    for (int c = 0; c < 14; c++) {
        half8 bf[4];
        #pragma unroll
        for (int nt = 0; nt < 4; nt++)
            bf[nt] = *(const half8*)(bp + c * 4096 + nt * 512);
        const int jw = r + dxA[c];
        const int js = jw & 15;
        const char* abase = smem + zyA[c] * 8704 + jw * 256;
        const char* a0 = abase + ((uA0 ^ js) << 4);
        const char* a1 = abase + ((uA1 ^ js) << 4);
        half8 af[2][2];
        af[0][0] = *(const half8*)a0;             // in_dim 2idp,   vt0
        af[0][1] = *(const half8*)(a0 + 4096);    // in_dim 2idp,   vt1 (+16 rows)
        af[1][0] = *(const half8*)a1;             // in_dim 2idp+1, vt0
        af[1][1] = *(const half8*)(a1 + 4096);    // in_dim 2idp+1, vt1
        __builtin_amdgcn_s_setprio(1);
        #pragma unroll
        for (int jj = 0; jj < 2; jj++)
            #pragma unroll
            for (int vt = 0; vt < 2; vt++)
                #pragma unroll
                for (int nt = 0; nt < 4; nt++)
                    acc[jj][vt][nt] = __builtin_amdgcn_mfma_f32_16x16x32_f16(
                        bf[nt], af[jj][vt], acc[jj][vt][nt], 0, 0, 0);
        __builtin_amdgcn_s_setprio(0);
    }

    __syncthreads();   // B1: slab reads done -> votes overlay

    // epilogue: ch = chh*64 + nt*16 + q*4 + e, in_dim = 2*idp + jj,
    // voxel = vt*16 + r. One ds_write_b64 per fragment.
    f32x4 cbq[4];
    #pragma unroll
    for (int nt = 0; nt < 4; nt++)
        cbq[nt] = *(const f32x4*)&cb[chh * 64 + nt * 16 + q * 4];
    #pragma unroll
    for (int jj = 0; jj < 2; jj++) {
        #pragma unroll
        for (int vt = 0; vt < 2; vt++) {
            _Float16* vp = &Vh[(vt * 16 + r) * 1032 + (2 * idp + jj) * 128
                               + chh * 64 + q * 4];
            #pragma unroll
            for (int nt = 0; nt < 4; nt++) {
                half4 hv;
                #pragma unroll
                for (int e = 0; e < 4; e++)
                    hv[e] = (_Float16)(acc[jj][vt][nt][e] + cbq[nt][e]);
                *(half4*)(vp + nt * 16) = hv;
            }
        }
    }
    __syncthreads();   // B2: vote writes visible

    // ============ routing (r13-verified, barrier-free): oo=t&7, half=bit3 =========
    const int oo   = t & 7;
    const int half = (t >> 3) & 1;
    const int vv   = t >> 4;              // voxel 0..31
    const int ib   = half << 2;           // own in_dims ib..ib+3

    f32x2 vf2[4][8];                      // [own i][atom pair] (all 16 atoms)
    #pragma unroll
    for (int ii = 0; ii < 4; ii++) {
        #pragma unroll
        for (int ah = 0; ah < 2; ah++) {
            const half8 hv =
                *(const half8*)&Vh[vv * 1032 + (ib + ii) * 128 + oo * 16 + ah * 8];
            #pragma unroll
            for (int k = 0; k < 4; k++) {
                f32x2 e; e[0] = (float)hv[2 * k]; e[1] = (float)hv[2 * k + 1];
                vf2[ii][ah * 4 + k] = e;
            }
        }
    }
    __syncthreads();   // B3: vote reads done -> OF may overlay vote region

    float vn[4];
    #pragma unroll
    for (int ii = 0; ii < 4; ii++) {
        f32x2 s = (f32x2)0.f;
        #pragma unroll
        for (int k = 0; k < 8; k++)
            s = __builtin_elementwise_fma(vf2[ii][k], vf2[ii][k], s);
        vn[ii] = sqrtf(s[0] + s[1]);
    }
    f32x2 bl2[8];
    #pragma unroll
    for (int k = 0; k < 8; k++)
        bl2[k] = *(const f32x2*)&bias[oo * 16 + 2 * k];

    float rt[4], lgr[4];
    #pragma unroll
    for (int ii = 0; ii < 4; ii++) { rt[ii] = 0.125f; lgr[ii] = 0.f; }
    f32x2 pre2[8];

    for (int it = 0; it < 3; it++) {
        #pragma unroll
        for (int k = 0; k < 8; k++) pre2[k] = (f32x2)0.f;
        #pragma unroll
        for (int ii = 0; ii < 4; ii++) {
            f32x2 rtv; rtv[0] = rt[ii]; rtv[1] = rt[ii];
            #pragma unroll
            for (int k = 0; k < 8; k++)
                pre2[k] = __builtin_elementwise_fma(rtv, vf2[ii][k], pre2[k]);
        }
        #pragma unroll
        for (int k = 0; k < 8; k++) {      // combine i-halves via lane^8 (VALU DPP)
            f32x2 cmb;
            cmb[0] = pre2[k][0] + ror8f(pre2[k][0]);
            cmb[1] = pre2[k][1] + ror8f(pre2[k][1]);
            pre2[k] = bl2[k] + cmb;
        }
        if (it == 2) break;

        f32x2 s2v = (f32x2)0.f;
        #pragma unroll
        for (int k = 0; k < 8; k++)
            s2v = __builtin_elementwise_fma(pre2[k], pre2[k], s2v);
        const float pn = sqrtf(s2v[0] + s2v[1]);

        #pragma unroll
        for (int ii = 0; ii < 4; ii++) {
            f32x2 dv = (f32x2)0.f;
            #pragma unroll
            for (int k = 0; k < 8; k++)
                dv = __builtin_elementwise_fma(pre2[k], vf2[ii][k], dv);
            lgr[ii] += __fdividef(dv[0] + dv[1], fmaxf(pn * vn[ii], 1e-8f));
            const float ex = __expf(lgr[ii]);   // |lgr| <= 2, no max-sub needed
            rt[ii] = __fdividef(ex, sum8(ex));  // softmax over o: 8-lane DPP
        }
    }

    // squash -> OF[vox][ch] (stride 130), then FULL-LINE coalesced store
    f32x2 s2v = (f32x2)0.f;
    #pragma unroll
    for (int k = 0; k < 8; k++)
        s2v = __builtin_elementwise_fma(pre2[k], pre2[k], s2v);
    const float n2 = s2v[0] + s2v[1];
    const float nn = sqrtf(n2);
    const float scale = __fdividef(n2, (1.f + n2) * (nn + 1e-12f));
    #pragma unroll
    for (int a = 0; a < 8; a++) {
        const float pv = half ? pre2[4 + (a >> 1)][a & 1]    // atoms 8..15
                              : pre2[(a >> 1)][a & 1];       // atoms 0..7
        OF[vv * 130 + oo * 16 + half * 8 + a] = pv * scale;
    }
    __syncthreads();   // B4: OF complete

    // readout: idx=(rep*512+t): ch=idx>>3 (plane), sg=idx&7 (w-quad).
    // Per instr: 8 ch-planes x 128B full lines (the r13 half-line RMW fix).
    #pragma unroll
    for (int rep = 0; rep < 2; rep++) {
        const int idx = rep * 512 + t;
        const int ch = idx >> 3, sg = idx & 7;
        f32x4 o0;
        #pragma unroll
        for (int e = 0; e < 4; e++) o0[e] = OF[(sg * 4 + e) * 130 + ch];
        float* op = out + ((size_t)((b * 8 + (ch >> 4)) * 16 + (ch & 15))) * 32768
                        + d * 1024 + h * 32 + sg * 4;
        *(f32x4*)op = o0;
    }
}

extern "C" void kernel_launch(void* const* d_in, const int* in_sizes, int n_in,
                              void* d_out, int out_size, void* d_ws, size_t ws_size,
                              hipStream_t stream) {
    const float* x    = (const float*)d_in[0];
    const float* cw   = (const float*)d_in[1];
    const float* cb   = (const float*)d_in[2];
    const float* bias = (const float*)d_in[3];
    float* out = (float*)d_out;
    _Float16* wh2 = (_Float16*)d_ws;                     // 114,688 B
    _Float16* xt  = (_Float16*)((char*)d_ws + 114688);   // 20,123,648 B

    hipLaunchKernelGGL(prep_all, dim3(744), dim3(256), 0, stream, x, cw, xt, wh2);
    hipLaunchKernelGGL(caps_mfma_kernel, dim3(2048), dim3(512), 0, stream,
                       xt, wh2, cb, bias, out);
}

// Round 14
// 162.805 us; speedup vs baseline: 1.8327x; 1.0698x over previous
//
#include <hip/hip_runtime.h>
#include <math.h>

// ConvSlimCapsule3D, round 18: r17 base (174.2us total, caps 104us) +
// 4-way channel split in the GEMM (L1->LDS traffic shift).
// Calibration (r16): L1 B-path ~34B/cyc effective vs LDS 128B/cyc -> move
// redundant operand traffic to LDS. Wave = (idp=wid>>2, chq=wid&3):
// 4 in_dims x 32 ch x 32 vox; bf loads/wave/chunk 4->2 (block L1 3.5->1.75MB/CU,
// ~-20us), af ds_reads 4->8 (+11us LDS). af loaded per-jj (8 transient regs,
// no r14-style spill; peak live ~90 < 128).
// Epilogue remapped; routing (r13/r17 DPP barrier-free), readout, prep unchanged.

typedef _Float16 half8 __attribute__((ext_vector_type(8)));
typedef _Float16 half4 __attribute__((ext_vector_type(4)));
typedef float f32x4 __attribute__((ext_vector_type(4)));
typedef float f32x2 __attribute__((ext_vector_type(2)));

__device__ __forceinline__ void gload_lds16(const void* g, void* l) {
    __builtin_amdgcn_global_load_lds(
        (const __attribute__((address_space(1))) void*)g,
        (__attribute__((address_space(3))) void*)l, 16, 0, 0);
}

template <int CTRL>
__device__ __forceinline__ float dppf(float x) {
    return __builtin_bit_cast(float, __builtin_amdgcn_update_dpp(
        0, __builtin_bit_cast(int, x), CTRL, 0xF, 0xF, true));
}
// sum across each aligned 8-lane group (VALU only; r10/r13-proven trio)
__device__ __forceinline__ float sum8(float x) {
    x += dppf<0xB1>(x);    // quad_perm(1,0,3,2): ^1
    x += dppf<0x4E>(x);    // quad_perm(2,3,0,1): ^2
    x += dppf<0x141>(x);   // row_half_mirror: completes the 8-group
    return x;
}
// lane^8 exchange (row_ror:8 within 16-lane row; r13-proven)
__device__ __forceinline__ float ror8f(float x) { return dppf<0x128>(x); }

// ---- prep_all: 744 blocks x 256 threads (r12, unchanged) ----
__global__ __launch_bounds__(256) void prep_all(const float* __restrict__ x,
                                                const float* __restrict__ cw,
                                                _Float16* __restrict__ xt,
                                                _Float16* __restrict__ wh2) {
    __shared__ _Float16 lds[272 * 136];   // 73,984 B (interior blocks only)
    const int t   = threadIdx.x;
    const int bid = blockIdx.x;

    if (bid < 256) {
        const int b  = bid >> 7;
        const int z  = (bid >> 2) & 31;
        const int y0 = (bid & 3) << 3;
        {
            const int rw = t >> 4, u = t & 15;
            const int y = rw >> 1, wp = (rw & 1) * 33;
            *(half8*)&lds[(y * 34 + wp) * 136 + u * 8] = (half8)(_Float16)0.f;
        }
        const float* xb = x + (size_t)b * 4194304 + z * 1024 + y0 * 32;
        #pragma unroll 4
        for (int i = 0; i < 32; i++) {
            const int idx4 = i * 256 + t;          // 0..8191
            const int ch = idx4 >> 6;              // 0..127
            const int y  = (idx4 >> 3) & 7;
            const int w4 = idx4 & 7;
            const f32x4 v = *(const f32x4*)(xb + (size_t)ch * 32768 + y * 32 + w4 * 4);
            const int rbase = y * 34 + w4 * 4 + 1;
            #pragma unroll
            for (int e = 0; e < 4; e++)
                lds[(rbase + e) * 136 + ch] = (_Float16)v[e];
        }
        __syncthreads();
        _Float16* dst = xt + ((size_t)((b * 34 + z + 1) * 34 + y0 + 1)) * 34 * 128;
        #pragma unroll
        for (int k = 0; k < 17; k++) {
            const int idx = k * 256 + t;
            const int vox = idx >> 4, u = idx & 15;
            *(half8*)(dst + (size_t)vox * 128 + u * 8) =
                *(const half8*)&lds[vox * 136 + u * 8];
        }
        return;
    }
    if (bid < 520) {
        const int rid = bid - 256;
        const int b = rid / 132, rr = rid - b * 132;
        int zp, yp;
        if (rr < 68) { zp = (rr >= 34) ? 33 : 0; yp = rr % 34; }
        else { const int r2 = rr - 68; zp = 1 + (r2 >> 1); yp = (r2 & 1) ? 33 : 0; }
        _Float16* dst = xt + ((size_t)((b * 34 + zp) * 34 + yp)) * 34 * 128;
        const half8 z8 = (half8)(_Float16)0.f;
        for (int idx = t; idx < 544; idx += 256)
            *(half8*)(dst + idx * 8) = z8;
        return;
    }
    {
        const int idx = (bid - 520) * 256 + t;
        const int n   = idx / 448;
        const int rem = idx - n * 448;
        const int c   = rem >> 5;
        const int k   = rem & 31;
        const int tp  = k >> 4, ca = k & 15;
        const int tap = 2 * c + tp;
        float v = (tap < 27) ? cw[n * 432 + ca * 27 + tap] : 0.0f;
        wh2[c * 4096 + n * 32 + k] = (_Float16)v;
    }
}

// =================== fused caps kernel =========================================
__global__ __launch_bounds__(512, 4) void caps_mfma_kernel(
    const _Float16* __restrict__ xt,  // (2,34,34,34,128) f16 padded
    const _Float16* __restrict__ wh2, // (14,128,32) f16 reordered
    const float* __restrict__ cb,     // (128,)
    const float* __restrict__ bias,   // (8,16)
    float* __restrict__ out)          // (2,8,16,32,32,32) f32
{
    // 78,848 B: slab = 306 live rows + 2 phantom, x 256B.
    // Votes (66,048B) overlay slab after B1; OF (32x130 f32) overlays after B3.
    __shared__ half8 slabv[4928];
    char* smem = (char*)slabv;
    _Float16* Vh = (_Float16*)slabv;
    float* OF = (float*)slabv;        // [vox 32][ch, stride 130] f32 = 16,640 B

    const int t  = threadIdx.x;
    const int bx = blockIdx.x;
    const int gid = ((bx & 7) << 8) | (bx >> 3);   // XCD-contiguous (2048 = 8*256)
    const int h = gid & 31;
    const int d = (gid >> 5) & 31;
    const int b = gid >> 10;

    const int wid = t >> 6, lane = t & 63;

    // stage slab: 308 rows x 256B via global_load_lds
    {
        const int lrow = lane >> 4;
        const int s    = lane & 15;
        const int bzd  = b * 34 + d;
        for (int i = wid; i < 77; i += 8) {
            const int rr0 = i << 2;
            const int rr  = rr0 + lrow;
            int zy = rr / 34;
            int j  = rr - zy * 34;
            if (rr >= 306) { zy = 0; j = 0; }
            const int dz  = (zy * 11) >> 5;
            const int dy  = zy - dz * 3;
            const int uu  = s ^ (j & 15);
            const unsigned off =
                ((((unsigned)(bzd + dz) * 34u + (unsigned)(h + dy)) * 34u
                  + (unsigned)j) << 8) + (unsigned)(uu << 4);
            gload_lds16((const char*)xt + off, smem + (rr0 << 8));
        }
    }
    __syncthreads();   // B0: slab staged

    // GEMM (swapped operands, 4-way ch split): wave = (idp = wid>>2, chq = wid&3):
    // 4 in_dims (4*idp+jj) x 32 channels (chq*32..) x 32 voxels.
    const int q = lane >> 4, r = lane & 15;
    const int qlow = q & 1, tphase = q >> 1;
    const int idp = wid >> 2, chq = wid & 3;

    int zyA[14], dxA[14];
    #pragma unroll
    for (int c = 0; c < 14; c++) {
        int tap = 2 * c + tphase;
        if (tap > 26) tap = 0;             // tap27: weight k-slots are zero
        const int dz = tap / 9, r9 = tap - dz * 9;
        const int dy = r9 / 3,  dxx = r9 - dy * 3;
        zyA[c] = dz * 3 + dy;
        dxA[c] = dxx;
    }
    const int uAb = 8 * idp + qlow;        // + 2*jj for in_dim 4*idp+jj
    const _Float16* bp = wh2 + (chq * 32 + r) * 32 + q * 8;  // + c*4096 + nt*512

    f32x4 acc[4][2][2];                    // [jj][vt voxel-half][nt ch-tile]
    #pragma unroll
    for (int i = 0; i < 4; i++)
        #pragma unroll
        for (int j = 0; j < 2; j++)
            #pragma unroll
            for (int k = 0; k < 2; k++) acc[i][j][k] = (f32x4)0.f;

    #pragma unroll
    for (int c = 0; c < 14; c++) {
        half8 bf[2];
        bf[0] = *(const half8*)(bp + c * 4096);
        bf[1] = *(const half8*)(bp + c * 4096 + 512);
        const int jw = r + dxA[c];
        const int js = jw & 15;
        const char* abase = smem + zyA[c] * 8704 + jw * 256;
        __builtin_amdgcn_s_setprio(1);
        #pragma unroll
        for (int jj = 0; jj < 4; jj++) {
            const char* aj = abase + (((uAb + 2 * jj) ^ js) << 4);
            const half8 af0 = *(const half8*)aj;            // vt0
            const half8 af1 = *(const half8*)(aj + 4096);   // vt1 (+16 rows)
            #pragma unroll
            for (int nt = 0; nt < 2; nt++) {
                acc[jj][0][nt] = __builtin_amdgcn_mfma_f32_16x16x32_f16(
                    bf[nt], af0, acc[jj][0][nt], 0, 0, 0);
                acc[jj][1][nt] = __builtin_amdgcn_mfma_f32_16x16x32_f16(
                    bf[nt], af1, acc[jj][1][nt], 0, 0, 0);
            }
        }
        __builtin_amdgcn_s_setprio(0);
    }

    __syncthreads();   // B1: slab reads done -> votes overlay

    // epilogue: ch = chq*32 + nt*16 + q*4 + e, in_dim = 4*idp + jj,
    // voxel = vt*16 + r. One ds_write_b64 per fragment.
    f32x4 cbq[2];
    #pragma unroll
    for (int nt = 0; nt < 2; nt++)
        cbq[nt] = *(const f32x4*)&cb[chq * 32 + nt * 16 + q * 4];
    #pragma unroll
    for (int jj = 0; jj < 4; jj++) {
        #pragma unroll
        for (int vt = 0; vt < 2; vt++) {
            _Float16* vp = &Vh[(vt * 16 + r) * 1032 + (4 * idp + jj) * 128
                               + chq * 32 + q * 4];
            #pragma unroll
            for (int nt = 0; nt < 2; nt++) {
                half4 hv;
                #pragma unroll
                for (int e = 0; e < 4; e++)
                    hv[e] = (_Float16)(acc[jj][vt][nt][e] + cbq[nt][e]);
                *(half4*)(vp + nt * 16) = hv;
            }
        }
    }
    __syncthreads();   // B2: vote writes visible

    // ============ routing (r13/r17-verified, barrier-free): oo=t&7, half=bit3 =====
    const int oo   = t & 7;
    const int half = (t >> 3) & 1;
    const int vv   = t >> 4;              // voxel 0..31
    const int ib   = half << 2;           // own in_dims ib..ib+3

    f32x2 vf2[4][8];                      // [own i][atom pair] (all 16 atoms)
    #pragma unroll
    for (int ii = 0; ii < 4; ii++) {
        #pragma unroll
        for (int ah = 0; ah < 2; ah++) {
            const half8 hv =
                *(const half8*)&Vh[vv * 1032 + (ib + ii) * 128 + oo * 16 + ah * 8];
            #pragma unroll
            for (int k = 0; k < 4; k++) {
                f32x2 e; e[0] = (float)hv[2 * k]; e[1] = (float)hv[2 * k + 1];
                vf2[ii][ah * 4 + k] = e;
            }
        }
    }
    __syncthreads();   // B3: vote reads done -> OF may overlay vote region

    float vn[4];
    #pragma unroll
    for (int ii = 0; ii < 4; ii++) {
        f32x2 s = (f32x2)0.f;
        #pragma unroll
        for (int k = 0; k < 8; k++)
            s = __builtin_elementwise_fma(vf2[ii][k], vf2[ii][k], s);
        vn[ii] = sqrtf(s[0] + s[1]);
    }
    f32x2 bl2[8];
    #pragma unroll
    for (int k = 0; k < 8; k++)
        bl2[k] = *(const f32x2*)&bias[oo * 16 + 2 * k];

    float rt[4], lgr[4];
    #pragma unroll
    for (int ii = 0; ii < 4; ii++) { rt[ii] = 0.125f; lgr[ii] = 0.f; }
    f32x2 pre2[8];

    for (int it = 0; it < 3; it++) {
        #pragma unroll
        for (int k = 0; k < 8; k++) pre2[k] = (f32x2)0.f;
        #pragma unroll
        for (int ii = 0; ii < 4; ii++) {
            f32x2 rtv; rtv[0] = rt[ii]; rtv[1] = rt[ii];
            #pragma unroll
            for (int k = 0; k < 8; k++)
                pre2[k] = __builtin_elementwise_fma(rtv, vf2[ii][k], pre2[k]);
        }
        #pragma unroll
        for (int k = 0; k < 8; k++) {      // combine i-halves via lane^8 (VALU DPP)
            f32x2 cmb;
            cmb[0] = pre2[k][0] + ror8f(pre2[k][0]);
            cmb[1] = pre2[k][1] + ror8f(pre2[k][1]);
            pre2[k] = bl2[k] + cmb;
        }
        if (it == 2) break;

        f32x2 s2v = (f32x2)0.f;
        #pragma unroll
        for (int k = 0; k < 8; k++)
            s2v = __builtin_elementwise_fma(pre2[k], pre2[k], s2v);
        const float pn = sqrtf(s2v[0] + s2v[1]);

        #pragma unroll
        for (int ii = 0; ii < 4; ii++) {
            f32x2 dv = (f32x2)0.f;
            #pragma unroll
            for (int k = 0; k < 8; k++)
                dv = __builtin_elementwise_fma(pre2[k], vf2[ii][k], dv);
            lgr[ii] += __fdividef(dv[0] + dv[1], fmaxf(pn * vn[ii], 1e-8f));
            const float ex = __expf(lgr[ii]);   // |lgr| <= 2, no max-sub needed
            rt[ii] = __fdividef(ex, sum8(ex));  // softmax over o: 8-lane DPP
        }
    }

    // squash -> OF[vox][ch] (stride 130), then FULL-LINE coalesced store
    f32x2 s2v = (f32x2)0.f;
    #pragma unroll
    for (int k = 0; k < 8; k++)
        s2v = __builtin_elementwise_fma(pre2[k], pre2[k], s2v);
    const float n2 = s2v[0] + s2v[1];
    const float nn = sqrtf(n2);
    const float scale = __fdividef(n2, (1.f + n2) * (nn + 1e-12f));
    #pragma unroll
    for (int a = 0; a < 8; a++) {
        const float pv = half ? pre2[4 + (a >> 1)][a & 1]    // atoms 8..15
                              : pre2[(a >> 1)][a & 1];       // atoms 0..7
        OF[vv * 130 + oo * 16 + half * 8 + a] = pv * scale;
    }
    __syncthreads();   // B4: OF complete

    // readout: idx=(rep*512+t): ch=idx>>3 (plane), sg=idx&7 (w-quad).
    // Per instr: 8 ch-planes x 128B full lines.
    #pragma unroll
    for (int rep = 0; rep < 2; rep++) {
        const int idx = rep * 512 + t;
        const int ch = idx >> 3, sg = idx & 7;
        f32x4 o0;
        #pragma unroll
        for (int e = 0; e < 4; e++) o0[e] = OF[(sg * 4 + e) * 130 + ch];
        float* op = out + ((size_t)((b * 8 + (ch >> 4)) * 16 + (ch & 15))) * 32768
                        + d * 1024 + h * 32 + sg * 4;
        *(f32x4*)op = o0;
    }
}

extern "C" void kernel_launch(void* const* d_in, const int* in_sizes, int n_in,
                              void* d_out, int out_size, void* d_ws, size_t ws_size,
                              hipStream_t stream) {
    const float* x    = (const float*)d_in[0];
    const float* cw   = (const float*)d_in[1];
    const float* cb   = (const float*)d_in[2];
    const float* bias = (const float*)d_in[3];
    float* out = (float*)d_out;
    _Float16* wh2 = (_Float16*)d_ws;                     // 114,688 B
    _Float16* xt  = (_Float16*)((char*)d_ws + 114688);   // 20,123,648 B

    hipLaunchKernelGGL(prep_all, dim3(744), dim3(256), 0, stream, x, cw, xt, wh2);
    hipLaunchKernelGGL(caps_mfma_kernel, dim3(2048), dim3(512), 0, stream,
                       xt, wh2, cb, bias, out);
}